// Round 6
// baseline (555.198 us; speedup 1.0000x reference)
//
#include <hip/hip_runtime.h>
#include <hip/hip_bf16.h>

#define M_CH 2
#define J_F 2000
#define I_F 2049
#define K_B 8
#define N_IT 5
#define NMF_EPS 1e-20f
#define IP_EPS 1e-20f
#define JCH 100     // j-chunks for D partials
#define JCHSZ 20    // 100*20 = 2000 exactly
#define PJT 100     // j-tiles in T-partial kernel
#define PJSZ 20     // 100*20 = 2000 exactly
#define IB 2304     // 9*256 padded i range

// ---------------- init: T[n][i][k], V[n][k][j], W[i] = eye ----------------
__global__ void k_init(const float* __restrict__ T0, const float* __restrict__ V0,
                       float* __restrict__ T, float* __restrict__ V, float* __restrict__ W) {
  int t = blockIdx.x * blockDim.x + threadIdx.x;
  int stride = gridDim.x * blockDim.x;
  for (int idx = t; idx < 2 * I_F * K_B; idx += stride) {
    int n = idx / (I_F * K_B);
    int r = idx % (I_F * K_B);
    int i = r / K_B, k = r % K_B;
    T[idx] = T0[(i * K_B + k) * M_CH + n];
  }
  for (int idx = t; idx < 2 * K_B * J_F; idx += stride) {
    int n = idx / (K_B * J_F);
    int r = idx % (K_B * J_F);
    int k = r / J_F, j = r % J_F;
    V[idx] = V0[(k * J_F + j) * M_CH + n];
  }
  for (int i = t; i < I_F; i += stride) {
    W[i * 8 + 0] = 1.f; W[i * 8 + 1] = 0.f; W[i * 8 + 2] = 0.f; W[i * 8 + 3] = 0.f;
    W[i * 8 + 4] = 0.f; W[i * 8 + 5] = 0.f; W[i * 8 + 6] = 1.f; W[i * 8 + 7] = 0.f;
  }
}

// ---- T-update partials; P = |W.X|^2 computed inline, never materialized ----
__global__ __launch_bounds__(256) void k_T_partial(const float2* __restrict__ X,
                                                   const float* __restrict__ W,
                                                   const float* __restrict__ T,
                                                   const float* __restrict__ V,
                                                   float* __restrict__ Tpart) {
  __shared__ float Vl[K_B][PJSZ];
  const int n = blockIdx.z;
  const int tid = threadIdx.x;
  const int j0 = blockIdx.y * PJSZ;
  for (int idx = tid; idx < K_B * PJSZ; idx += 256) {
    int k = idx / PJSZ, jj = idx % PJSZ;
    Vl[k][jj] = V[((size_t)n * K_B + k) * J_F + j0 + jj];
  }
  __syncthreads();
  const int i = blockIdx.x * 256 + tid;
  if (i >= I_F) return;
  float tr[K_B];
#pragma unroll
  for (int k = 0; k < K_B; ++k) tr[k] = T[((size_t)n * I_F + i) * 8 + k];
  const float4 w = ((const float4*)W)[i * 2 + n];
  float num[K_B] = {}, den[K_B] = {};
  const float2* Xa = X + i;
  const float2* Xb = X + (size_t)J_F * I_F + i;
#pragma unroll 4
  for (int jj = 0; jj < PJSZ; ++jj) {
    const size_t jo = (size_t)(j0 + jj) * I_F;
    float2 x0 = Xa[jo];
    float2 x1 = Xb[jo];
    float yr = w.x * x0.x - w.y * x0.y + w.z * x1.x - w.w * x1.y;
    float yi = w.x * x0.y + w.y * x0.x + w.z * x1.y + w.w * x1.x;
    float p = yr * yr + yi * yi;
    float R = 0.f;
#pragma unroll
    for (int k = 0; k < K_B; ++k) R += tr[k] * Vl[k][jj];
    float a = p / (R * R);
    float b = 1.0f / R;
#pragma unroll
    for (int k = 0; k < K_B; ++k) { num[k] += a * Vl[k][jj]; den[k] += b * Vl[k][jj]; }
  }
  float* base = Tpart + (((size_t)n * PJT + blockIdx.y) * IB + i) * 16;
  *(float4*)(base + 0)  = make_float4(num[0], num[1], num[2], num[3]);
  *(float4*)(base + 4)  = make_float4(num[4], num[5], num[6], num[7]);
  *(float4*)(base + 8)  = make_float4(den[0], den[1], den[2], den[3]);
  *(float4*)(base + 12) = make_float4(den[4], den[5], den[6], den[7]);
}

// ---------------- finish T update from partials ----------------
__global__ __launch_bounds__(256) void k_t_finish(const float* __restrict__ Tpart,
                                                  float* __restrict__ T) {
  int t = blockIdx.x * 256 + threadIdx.x;
  if (t >= 2 * I_F * K_B) return;
  int n = t / (I_F * K_B);
  int r = t % (I_F * K_B);
  int i = r >> 3, k = r & 7;
  float num = 0.f, den = 0.f;
  const float* p = Tpart + (((size_t)n * PJT) * IB + i) * 16;
#pragma unroll 10
  for (int jt = 0; jt < PJT; ++jt) {
    num += p[(size_t)jt * IB * 16 + k];
    den += p[(size_t)jt * IB * 16 + 8 + k];
  }
  float told = T[t];
  T[t] = fmaxf(told * sqrtf(num / den), NMF_EPS);
}

// -- V update: block per j, both n, recompute P inline, full i-reduce, in place --
__global__ __launch_bounds__(256) void k_v_update(const float2* __restrict__ X,
                                                  const float* __restrict__ W,
                                                  const float* __restrict__ T,
                                                  float* __restrict__ V) {
  const int j = blockIdx.x;
  const int tid = threadIdx.x;
  float vold0[K_B], vold1[K_B];
#pragma unroll
  for (int k = 0; k < K_B; ++k) {
    vold0[k] = V[(size_t)k * J_F + j];
    vold1[k] = V[(size_t)(K_B + k) * J_F + j];
  }
  float num0[K_B] = {}, den0[K_B] = {}, num1[K_B] = {}, den1[K_B] = {};
  const float2* Xa = X + (size_t)j * I_F;
  const float2* Xb = X + (size_t)(J_F + j) * I_F;
  const float* T1 = T + (size_t)I_F * K_B;
  for (int i = tid; i < I_F; i += 256) {
    float2 x0 = Xa[i];
    float2 x1 = Xb[i];
    const float4 wa = ((const float4*)W)[i * 2];
    const float4 wb = ((const float4*)W)[i * 2 + 1];
    float yr = wa.x * x0.x - wa.y * x0.y + wa.z * x1.x - wa.w * x1.y;
    float yi = wa.x * x0.y + wa.y * x0.x + wa.z * x1.y + wa.w * x1.x;
    float p0 = yr * yr + yi * yi;
    float zr = wb.x * x0.x - wb.y * x0.y + wb.z * x1.x - wb.w * x1.y;
    float zi = wb.x * x0.y + wb.y * x0.x + wb.z * x1.y + wb.w * x1.x;
    float p1 = zr * zr + zi * zi;
    const float4 ta = *(const float4*)&T[i * 8];
    const float4 tb = *(const float4*)&T[i * 8 + 4];
    const float4 tc = *(const float4*)&T1[i * 8];
    const float4 td = *(const float4*)&T1[i * 8 + 4];
    float t0[K_B] = {ta.x, ta.y, ta.z, ta.w, tb.x, tb.y, tb.z, tb.w};
    float t1[K_B] = {tc.x, tc.y, tc.z, tc.w, td.x, td.y, td.z, td.w};
    float R0 = 0.f, R1 = 0.f;
#pragma unroll
    for (int k = 0; k < K_B; ++k) { R0 += t0[k] * vold0[k]; R1 += t1[k] * vold1[k]; }
    float a0 = p0 / (R0 * R0), b0 = 1.0f / R0;
    float a1 = p1 / (R1 * R1), b1 = 1.0f / R1;
#pragma unroll
    for (int k = 0; k < K_B; ++k) {
      num0[k] += a0 * t0[k]; den0[k] += b0 * t0[k];
      num1[k] += a1 * t1[k]; den1[k] += b1 * t1[k];
    }
  }
  __shared__ float red[4][32];
  const int lane = tid & 63, wid = tid >> 6;
#pragma unroll
  for (int k = 0; k < K_B; ++k) {
    float a0 = num0[k], b0 = den0[k], a1 = num1[k], b1 = den1[k];
#pragma unroll
    for (int off = 32; off > 0; off >>= 1) {
      a0 += __shfl_xor(a0, off, 64);
      b0 += __shfl_xor(b0, off, 64);
      a1 += __shfl_xor(a1, off, 64);
      b1 += __shfl_xor(b1, off, 64);
    }
    if (lane == 0) {
      red[wid][k] = a0; red[wid][8 + k] = b0;
      red[wid][16 + k] = a1; red[wid][24 + k] = b1;
    }
  }
  __syncthreads();
  if (tid < 32) red[0][tid] = red[0][tid] + red[1][tid] + red[2][tid] + red[3][tid];
  __syncthreads();
  if (tid < 16) {
    int n = tid >> 3, k = tid & 7;
    float num = red[0][n * 16 + k];
    float den = red[0][n * 16 + 8 + k];
    size_t idx = ((size_t)n * K_B + k) * J_F + j;
    float vo = V[idx];
    V[idx] = fmaxf(vo * sqrtf(num / den), NMF_EPS);
  }
}

// -------- weighted covariance partials; one n per z-block --------
__global__ __launch_bounds__(256) void k_d_partial(const float2* __restrict__ X,
                                                   const float* __restrict__ T,
                                                   const float* __restrict__ V,
                                                   float* __restrict__ Dpart) {
  __shared__ float Vl[K_B][JCHSZ];
  const int n = blockIdx.z;
  const int tid = threadIdx.x;
  const int j0 = blockIdx.y * JCHSZ;
  for (int idx = tid; idx < K_B * JCHSZ; idx += 256) {
    int k = idx / JCHSZ, jj = idx % JCHSZ;
    Vl[k][jj] = V[((size_t)n * K_B + k) * J_F + j0 + jj];
  }
  __syncthreads();
  const int i = blockIdx.x * 256 + tid;
  if (i >= I_F) return;
  float tr[K_B];
#pragma unroll
  for (int k = 0; k < K_B; ++k) tr[k] = T[((size_t)n * I_F + i) * K_B + k];
  float a00 = 0.f, a11 = 0.f, a01r = 0.f, a01i = 0.f;
  const float2* Xa = X + i;
  const float2* Xb = X + (size_t)J_F * I_F + i;
#pragma unroll 4
  for (int jj = 0; jj < JCHSZ; ++jj) {
    const size_t jo = (size_t)(j0 + jj) * I_F;
    float R = 0.f;
#pragma unroll
    for (int k = 0; k < K_B; ++k) R += tr[k] * Vl[k][jj];
    float wv = 1.0f / (R + IP_EPS);
    float2 x0 = Xa[jo];
    float2 x1 = Xb[jo];
    a00 += wv * (x0.x * x0.x + x0.y * x0.y);
    a11 += wv * (x1.x * x1.x + x1.y * x1.y);
    a01r += wv * (x0.x * x1.x + x0.y * x1.y);
    a01i += wv * (x0.y * x1.x - x0.x * x1.y);
  }
  ((float4*)Dpart)[((size_t)n * JCH + blockIdx.y) * I_F + i] =
      make_float4(a00, a11, a01r, a01i);
}

// -------- combine D + sequential 2x2 complex solves (n=0 then n=1) --------
__global__ __launch_bounds__(256) void k_d_solve(const float* __restrict__ Dpart,
                                                 float* __restrict__ W) {
  const int i = blockIdx.x * 256 + threadIdx.x;
  if (i >= I_F) return;
  float4 wa = ((const float4*)W)[i * 2];
  float4 wb = ((const float4*)W)[i * 2 + 1];
  float w00r = wa.x, w00i = wa.y, w01r = wa.z, w01i = wa.w;
  float w10r = wb.x, w10i = wb.y, w11r = wb.z, w11i = wb.w;
  const float invJ = 1.0f / (float)J_F;
#pragma unroll
  for (int n = 0; n < 2; ++n) {
    float d00 = 0.f, d11 = 0.f, d01r = 0.f, d01i = 0.f;
    const float4* dp = (const float4*)Dpart + (size_t)n * JCH * I_F + i;
#pragma unroll 10
    for (int c = 0; c < JCH; ++c) {
      float4 d = dp[(size_t)c * I_F];
      d00 += d.x; d11 += d.y; d01r += d.z; d01i += d.w;
    }
    d00 = d00 * invJ + IP_EPS;
    d11 = d11 * invJ + IP_EPS;
    d01r *= invJ; d01i *= invJ;
    float A00r = w00r * d00 + (w01r * d01r + w01i * d01i);
    float A00i = w00i * d00 + (w01i * d01r - w01r * d01i);
    float A01r = (w00r * d01r - w00i * d01i) + w01r * d11;
    float A01i = (w00r * d01i + w00i * d01r) + w01i * d11;
    float A10r = w10r * d00 + (w11r * d01r + w11i * d01i);
    float A10i = w10i * d00 + (w11i * d01r - w11r * d01i);
    float A11r = (w10r * d01r - w10i * d01i) + w11r * d11;
    float A11i = (w10r * d01i + w10i * d01r) + w11i * d11;
    float detr = (A00r * A11r - A00i * A11i) - (A01r * A10r - A01i * A10i);
    float deti = (A00r * A11i + A00i * A11r) - (A01r * A10i + A01i * A10r);
    float idet = 1.0f / (detr * detr + deti * deti);
    float n0r, n0i, n1r, n1i;
    if (n == 0) { n0r = A11r; n0i = A11i; n1r = -A10r; n1i = -A10i; }
    else        { n0r = -A01r; n0i = -A01i; n1r = A00r; n1i = A00i; }
    float b0r = (n0r * detr + n0i * deti) * idet;
    float b0i = (n0i * detr - n0r * deti) * idet;
    float b1r = (n1r * detr + n1i * deti) * idet;
    float b1i = (n1i * detr - n1r * deti) * idet;
    float cr = d01r * b1r - d01i * b1i;
    float ci = d01r * b1i + d01i * b1r;
    float quad = d00 * (b0r * b0r + b0i * b0i) + d11 * (b1r * b1r + b1i * b1i)
               + 2.0f * (b0r * cr + b0i * ci);
    float s = 1.0f / sqrtf(quad + IP_EPS);
    if (n == 0) { w00r = b0r * s; w00i = -b0i * s; w01r = b1r * s; w01i = -b1i * s; }
    else        { w10r = b0r * s; w10i = -b0i * s; w11r = b1r * s; w11i = -b1i * s; }
  }
  ((float4*)W)[i * 2]     = make_float4(w00r, w00i, w01r, w01i);
  ((float4*)W)[i * 2 + 1] = make_float4(w10r, w10i, w11r, w11i);
}

// ---------------- final: out[n][j][i][2] = Y[i,n,j] ----------------
__global__ __launch_bounds__(256) void k_final(const float2* __restrict__ X,
                                               const float* __restrict__ W,
                                               float2* __restrict__ out) {
  const int i = blockIdx.x * 256 + threadIdx.x;
  if (i >= I_F) return;
  const float4 wa = ((const float4*)W)[i * 2];
  const float4 wb = ((const float4*)W)[i * 2 + 1];
  const int j0 = blockIdx.y * 8;
  const int jend = min(8, J_F - j0);
  for (int jj = 0; jj < jend; ++jj) {
    const int j = j0 + jj;
    float2 x0 = X[(size_t)j * I_F + i];
    float2 x1 = X[(size_t)(J_F + j) * I_F + i];
    float y0r = wa.x * x0.x - wa.y * x0.y + wa.z * x1.x - wa.w * x1.y;
    float y0i = wa.x * x0.y + wa.y * x0.x + wa.z * x1.y + wa.w * x1.x;
    out[(size_t)j * I_F + i] = make_float2(y0r, y0i);
    float y1r = wb.x * x0.x - wb.y * x0.y + wb.z * x1.x - wb.w * x1.y;
    float y1i = wb.x * x0.y + wb.y * x0.x + wb.z * x1.y + wb.w * x1.x;
    out[(size_t)(J_F + j) * I_F + i] = make_float2(y1r, y1i);
  }
}

extern "C" void kernel_launch(void* const* d_in, const int* in_sizes, int n_in,
                              void* d_out, int out_size, void* d_ws, size_t ws_size,
                              hipStream_t stream) {
  const float2* X = (const float2*)d_in[0];
  const float* T0 = (const float*)d_in[1];
  const float* V0 = (const float*)d_in[2];
  char* ws = (char*)d_ws;
  size_t off = 0;
  auto alloc = [&](size_t bytes) -> void* {
    void* p = ws + off;
    off = (off + bytes + 255) & ~(size_t)255;
    return p;
  };
  float* W = (float*)alloc((size_t)I_F * 8 * 4);
  float* T = (float*)alloc((size_t)2 * I_F * K_B * 4);
  float* V = (float*)alloc((size_t)2 * K_B * J_F * 4);
  // Tpart (29.5 MB) and Dpart (6.6 MB) have disjoint lifetimes -> share
  float* Scr = (float*)alloc((size_t)2 * PJT * IB * 16 * 4);
  float* Tpart = Scr;
  float* Dpart = Scr;

  k_init<<<128, 256, 0, stream>>>(T0, V0, T, V, W);
  for (int it = 0; it < N_IT; ++it) {
    k_T_partial<<<dim3(9, PJT, 2), 256, 0, stream>>>(X, W, T, V, Tpart);
    k_t_finish<<<129, 256, 0, stream>>>(Tpart, T);
    k_v_update<<<J_F, 256, 0, stream>>>(X, W, T, V);
    k_d_partial<<<dim3(9, JCH, 2), 256, 0, stream>>>(X, T, V, Dpart);
    k_d_solve<<<9, 256, 0, stream>>>(Dpart, W);
  }
  k_final<<<dim3(9, 250), 256, 0, stream>>>(X, W, (float2*)d_out);
}

// Round 7
// 553.120 us; speedup vs baseline: 1.0038x; 1.0038x over previous
//
#include <hip/hip_runtime.h>
#include <hip/hip_bf16.h>

#define M_CH 2
#define J_F 2000
#define I_F 2049
#define K_B 8
#define N_IT 5
#define NMF_EPS 1e-20f
#define IP_EPS 1e-20f
#define JCH 100     // j-chunks for D partials
#define JCHSZ 20    // 100*20 = 2000 exactly
#define PJT 100     // j-tiles in T-partial kernel
#define PJSZ 20     // 100*20 = 2000 exactly
#define IB 2304     // 9*256 padded i range
#define PF 4        // software-pipeline prefetch depth

// ---------------- init: T[n][i][k], V[n][k][j], W[i] = eye ----------------
__global__ void k_init(const float* __restrict__ T0, const float* __restrict__ V0,
                       float* __restrict__ T, float* __restrict__ V, float* __restrict__ W) {
  int t = blockIdx.x * blockDim.x + threadIdx.x;
  int stride = gridDim.x * blockDim.x;
  for (int idx = t; idx < 2 * I_F * K_B; idx += stride) {
    int n = idx / (I_F * K_B);
    int r = idx % (I_F * K_B);
    int i = r / K_B, k = r % K_B;
    T[idx] = T0[(i * K_B + k) * M_CH + n];
  }
  for (int idx = t; idx < 2 * K_B * J_F; idx += stride) {
    int n = idx / (K_B * J_F);
    int r = idx % (K_B * J_F);
    int k = r / J_F, j = r % J_F;
    V[idx] = V0[(k * J_F + j) * M_CH + n];
  }
  for (int i = t; i < I_F; i += stride) {
    W[i * 8 + 0] = 1.f; W[i * 8 + 1] = 0.f; W[i * 8 + 2] = 0.f; W[i * 8 + 3] = 0.f;
    W[i * 8 + 4] = 0.f; W[i * 8 + 5] = 0.f; W[i * 8 + 6] = 1.f; W[i * 8 + 7] = 0.f;
  }
}

// ---- P[n][j][i] + lane-local T partials; flat grid w/ XCD pair-swizzle ----
__global__ __launch_bounds__(256) void k_T_partial(const float2* __restrict__ X,
                                                   const float* __restrict__ W,
                                                   const float* __restrict__ T,
                                                   const float* __restrict__ V,
                                                   float* __restrict__ P,
                                                   float* __restrict__ Tpart) {
  // flat 1800 blocks -> (xb 0..8, yb 0..99, n 0..1); (n=0,n=1) pairs same XCD
  const int wid = blockIdx.x;
  const int w = (wid % 8) * 225 + wid / 8;
  const int n = w & 1;
  const int rest = w >> 1;
  const int xb = rest % 9, yb = rest / 9;
  __shared__ float Vl[K_B][PJSZ];
  const int tid = threadIdx.x;
  const int j0 = yb * PJSZ;
  for (int idx = tid; idx < K_B * PJSZ; idx += 256) {
    int k = idx / PJSZ, jj = idx % PJSZ;
    Vl[k][jj] = V[((size_t)n * K_B + k) * J_F + j0 + jj];
  }
  __syncthreads();
  const int i = xb * 256 + tid;
  if (i >= I_F) return;
  float tr[K_B];
#pragma unroll
  for (int k = 0; k < K_B; ++k) tr[k] = T[((size_t)n * I_F + i) * 8 + k];
  const float4 wv4 = ((const float4*)W)[i * 2 + n];
  float num[K_B] = {}, den[K_B] = {};
  const float2* Xa = X + i;
  const float2* Xb = X + (size_t)J_F * I_F + i;
  float* Pn = P + ((size_t)n * J_F + j0) * I_F + i;
  float2 pa[PF], pb[PF];
#pragma unroll
  for (int g = 0; g < PF; ++g) {
    size_t jo = (size_t)(j0 + g) * I_F;
    pa[g] = Xa[jo]; pb[g] = Xb[jo];
  }
  for (int base = 0; base < PJSZ; base += PF) {
    float2 na_[PF], nb_[PF];
    const bool more = (base + PF) < PJSZ;
    if (more) {
#pragma unroll
      for (int g = 0; g < PF; ++g) {
        size_t jo = (size_t)(j0 + base + PF + g) * I_F;
        na_[g] = Xa[jo]; nb_[g] = Xb[jo];
      }
    }
#pragma unroll
    for (int g = 0; g < PF; ++g) {
      const int jj = base + g;
      float2 x0 = pa[g], x1 = pb[g];
      float yr = wv4.x * x0.x - wv4.y * x0.y + wv4.z * x1.x - wv4.w * x1.y;
      float yi = wv4.x * x0.y + wv4.y * x0.x + wv4.z * x1.y + wv4.w * x1.x;
      float p = yr * yr + yi * yi;
      Pn[(size_t)jj * I_F] = p;
      float R = 0.f;
#pragma unroll
      for (int k = 0; k < K_B; ++k) R += tr[k] * Vl[k][jj];
      float a = p / (R * R);
      float b = 1.0f / R;
#pragma unroll
      for (int k = 0; k < K_B; ++k) { num[k] += a * Vl[k][jj]; den[k] += b * Vl[k][jj]; }
    }
    if (more) {
#pragma unroll
      for (int g = 0; g < PF; ++g) { pa[g] = na_[g]; pb[g] = nb_[g]; }
    }
  }
  float* base_ = Tpart + (((size_t)n * PJT + yb) * IB + i) * 16;
  *(float4*)(base_ + 0)  = make_float4(num[0], num[1], num[2], num[3]);
  *(float4*)(base_ + 4)  = make_float4(num[4], num[5], num[6], num[7]);
  *(float4*)(base_ + 8)  = make_float4(den[0], den[1], den[2], den[3]);
  *(float4*)(base_ + 12) = make_float4(den[4], den[5], den[6], den[7]);
}

// ---------------- finish T update from partials (ILP-4) ----------------
__global__ __launch_bounds__(256) void k_t_finish(const float* __restrict__ Tpart,
                                                  float* __restrict__ T) {
  int t = blockIdx.x * 256 + threadIdx.x;
  if (t >= 2 * I_F * K_B) return;
  int n = t / (I_F * K_B);
  int r = t % (I_F * K_B);
  int i = r >> 3, k = r & 7;
  const float* p = Tpart + (((size_t)n * PJT) * IB + i) * 16;
  const size_t S = (size_t)IB * 16;
  float n0 = 0.f, n1 = 0.f, n2 = 0.f, n3 = 0.f;
  float d0 = 0.f, d1 = 0.f, d2 = 0.f, d3 = 0.f;
  for (int jt = 0; jt < PJT; jt += 4) {
    n0 += p[jt * S + k];       d0 += p[jt * S + 8 + k];
    n1 += p[(jt + 1) * S + k]; d1 += p[(jt + 1) * S + 8 + k];
    n2 += p[(jt + 2) * S + k]; d2 += p[(jt + 2) * S + 8 + k];
    n3 += p[(jt + 3) * S + k]; d3 += p[(jt + 3) * S + 8 + k];
  }
  float num = (n0 + n1) + (n2 + n3);
  float den = (d0 + d1) + (d2 + d3);
  float told = T[t];
  T[t] = fmaxf(told * sqrtf(num / den), NMF_EPS);
}

// -- V update: block = (2 j's, one n), reads P, full i-reduce, in place --
__global__ __launch_bounds__(256) void k_v_update(const float* __restrict__ P,
                                                  const float* __restrict__ T,
                                                  float* __restrict__ V) {
  const int j0 = blockIdx.x * 2;
  const int n = blockIdx.y;
  const int tid = threadIdx.x;
  const float* P0 = P + ((size_t)n * J_F + j0) * I_F;
  const float* P1 = P0 + I_F;
  const float* Tn = T + (size_t)n * I_F * K_B;
  float vold[2][K_B];
#pragma unroll
  for (int k = 0; k < K_B; ++k) {
    vold[0][k] = V[((size_t)n * K_B + k) * J_F + j0];
    vold[1][k] = V[((size_t)n * K_B + k) * J_F + j0 + 1];
  }
  float num[2][K_B] = {}, den[2][K_B] = {};
#pragma unroll 2
  for (int i = tid; i < I_F; i += 256) {
    float p0 = P0[i];
    float p1 = P1[i];
    const float4 ta = *(const float4*)&Tn[i * 8];
    const float4 tb = *(const float4*)&Tn[i * 8 + 4];
    float tk[K_B] = {ta.x, ta.y, ta.z, ta.w, tb.x, tb.y, tb.z, tb.w};
    float R0 = 0.f, R1 = 0.f;
#pragma unroll
    for (int k = 0; k < K_B; ++k) { R0 += tk[k] * vold[0][k]; R1 += tk[k] * vold[1][k]; }
    float a0 = p0 / (R0 * R0), b0 = 1.0f / R0;
    float a1 = p1 / (R1 * R1), b1 = 1.0f / R1;
#pragma unroll
    for (int k = 0; k < K_B; ++k) {
      num[0][k] += a0 * tk[k]; den[0][k] += b0 * tk[k];
      num[1][k] += a1 * tk[k]; den[1][k] += b1 * tk[k];
    }
  }
  __shared__ float red[4][32];
  const int lane = tid & 63, wid = tid >> 6;
#pragma unroll
  for (int k = 0; k < K_B; ++k) {
    float a0 = num[0][k], b0 = den[0][k], a1 = num[1][k], b1 = den[1][k];
#pragma unroll
    for (int off = 32; off > 0; off >>= 1) {
      a0 += __shfl_xor(a0, off, 64);
      b0 += __shfl_xor(b0, off, 64);
      a1 += __shfl_xor(a1, off, 64);
      b1 += __shfl_xor(b1, off, 64);
    }
    if (lane == 0) {
      red[wid][k] = a0; red[wid][8 + k] = b0;
      red[wid][16 + k] = a1; red[wid][24 + k] = b1;
    }
  }
  __syncthreads();
  if (tid < 32) red[0][tid] = red[0][tid] + red[1][tid] + red[2][tid] + red[3][tid];
  __syncthreads();
  if (tid < 16) {
    int jl = tid >> 3, k = tid & 7;
    float nu = red[0][jl * 16 + k];
    float de = red[0][jl * 16 + 8 + k];
    size_t idx = ((size_t)n * K_B + k) * J_F + j0 + jl;
    float vo = V[idx];
    V[idx] = fmaxf(vo * sqrtf(nu / de), NMF_EPS);
  }
}

// -------- weighted covariance partials; flat grid w/ XCD pair-swizzle --------
__global__ __launch_bounds__(256) void k_d_partial(const float2* __restrict__ X,
                                                   const float* __restrict__ T,
                                                   const float* __restrict__ V,
                                                   float* __restrict__ Dpart) {
  const int wid = blockIdx.x;
  const int w = (wid % 8) * 225 + wid / 8;
  const int n = w & 1;
  const int rest = w >> 1;
  const int xb = rest % 9, yb = rest / 9;
  __shared__ float Vl[K_B][JCHSZ];
  const int tid = threadIdx.x;
  const int j0 = yb * JCHSZ;
  for (int idx = tid; idx < K_B * JCHSZ; idx += 256) {
    int k = idx / JCHSZ, jj = idx % JCHSZ;
    Vl[k][jj] = V[((size_t)n * K_B + k) * J_F + j0 + jj];
  }
  __syncthreads();
  const int i = xb * 256 + tid;
  if (i >= I_F) return;
  float tr[K_B];
#pragma unroll
  for (int k = 0; k < K_B; ++k) tr[k] = T[((size_t)n * I_F + i) * K_B + k];
  float a00 = 0.f, a11 = 0.f, a01r = 0.f, a01i = 0.f;
  const float2* Xa = X + i;
  const float2* Xb = X + (size_t)J_F * I_F + i;
  float2 pa[PF], pb[PF];
#pragma unroll
  for (int g = 0; g < PF; ++g) {
    size_t jo = (size_t)(j0 + g) * I_F;
    pa[g] = Xa[jo]; pb[g] = Xb[jo];
  }
  for (int base = 0; base < JCHSZ; base += PF) {
    float2 na_[PF], nb_[PF];
    const bool more = (base + PF) < JCHSZ;
    if (more) {
#pragma unroll
      for (int g = 0; g < PF; ++g) {
        size_t jo = (size_t)(j0 + base + PF + g) * I_F;
        na_[g] = Xa[jo]; nb_[g] = Xb[jo];
      }
    }
#pragma unroll
    for (int g = 0; g < PF; ++g) {
      const int jj = base + g;
      float R = 0.f;
#pragma unroll
      for (int k = 0; k < K_B; ++k) R += tr[k] * Vl[k][jj];
      float wv = 1.0f / (R + IP_EPS);
      float2 x0 = pa[g], x1 = pb[g];
      a00 += wv * (x0.x * x0.x + x0.y * x0.y);
      a11 += wv * (x1.x * x1.x + x1.y * x1.y);
      a01r += wv * (x0.x * x1.x + x0.y * x1.y);
      a01i += wv * (x0.y * x1.x - x0.x * x1.y);
    }
    if (more) {
#pragma unroll
      for (int g = 0; g < PF; ++g) { pa[g] = na_[g]; pb[g] = nb_[g]; }
    }
  }
  ((float4*)Dpart)[((size_t)n * JCH + yb) * I_F + i] =
      make_float4(a00, a11, a01r, a01i);
}

// -------- combine D (ILP-4) + sequential 2x2 complex solves --------
__global__ __launch_bounds__(256) void k_d_solve(const float* __restrict__ Dpart,
                                                 float* __restrict__ W) {
  const int i = blockIdx.x * 256 + threadIdx.x;
  if (i >= I_F) return;
  float4 wa = ((const float4*)W)[i * 2];
  float4 wb = ((const float4*)W)[i * 2 + 1];
  float w00r = wa.x, w00i = wa.y, w01r = wa.z, w01i = wa.w;
  float w10r = wb.x, w10i = wb.y, w11r = wb.z, w11i = wb.w;
  const float invJ = 1.0f / (float)J_F;
#pragma unroll
  for (int n = 0; n < 2; ++n) {
    const float4* dp = (const float4*)Dpart + (size_t)n * JCH * I_F + i;
    float s0x = 0.f, s0y = 0.f, s0z = 0.f, s0w = 0.f;
    float s1x = 0.f, s1y = 0.f, s1z = 0.f, s1w = 0.f;
    float s2x = 0.f, s2y = 0.f, s2z = 0.f, s2w = 0.f;
    float s3x = 0.f, s3y = 0.f, s3z = 0.f, s3w = 0.f;
    for (int c = 0; c < JCH; c += 4) {
      float4 e0 = dp[(size_t)c * I_F];
      float4 e1 = dp[(size_t)(c + 1) * I_F];
      float4 e2 = dp[(size_t)(c + 2) * I_F];
      float4 e3 = dp[(size_t)(c + 3) * I_F];
      s0x += e0.x; s0y += e0.y; s0z += e0.z; s0w += e0.w;
      s1x += e1.x; s1y += e1.y; s1z += e1.z; s1w += e1.w;
      s2x += e2.x; s2y += e2.y; s2z += e2.z; s2w += e2.w;
      s3x += e3.x; s3y += e3.y; s3z += e3.z; s3w += e3.w;
    }
    float d00 = (s0x + s1x) + (s2x + s3x);
    float d11 = (s0y + s1y) + (s2y + s3y);
    float d01r = (s0z + s1z) + (s2z + s3z);
    float d01i = (s0w + s1w) + (s2w + s3w);
    d00 = d00 * invJ + IP_EPS;
    d11 = d11 * invJ + IP_EPS;
    d01r *= invJ; d01i *= invJ;
    float A00r = w00r * d00 + (w01r * d01r + w01i * d01i);
    float A00i = w00i * d00 + (w01i * d01r - w01r * d01i);
    float A01r = (w00r * d01r - w00i * d01i) + w01r * d11;
    float A01i = (w00r * d01i + w00i * d01r) + w01i * d11;
    float A10r = w10r * d00 + (w11r * d01r + w11i * d01i);
    float A10i = w10i * d00 + (w11i * d01r - w11r * d01i);
    float A11r = (w10r * d01r - w10i * d01i) + w11r * d11;
    float A11i = (w10r * d01i + w10i * d01r) + w11i * d11;
    float detr = (A00r * A11r - A00i * A11i) - (A01r * A10r - A01i * A10i);
    float deti = (A00r * A11i + A00i * A11r) - (A01r * A10i + A01i * A10r);
    float idet = 1.0f / (detr * detr + deti * deti);
    float n0r, n0i, n1r, n1i;
    if (n == 0) { n0r = A11r; n0i = A11i; n1r = -A10r; n1i = -A10i; }
    else        { n0r = -A01r; n0i = -A01i; n1r = A00r; n1i = A00i; }
    float b0r = (n0r * detr + n0i * deti) * idet;
    float b0i = (n0i * detr - n0r * deti) * idet;
    float b1r = (n1r * detr + n1i * deti) * idet;
    float b1i = (n1i * detr - n1r * deti) * idet;
    float cr = d01r * b1r - d01i * b1i;
    float ci = d01r * b1i + d01i * b1r;
    float quad = d00 * (b0r * b0r + b0i * b0i) + d11 * (b1r * b1r + b1i * b1i)
               + 2.0f * (b0r * cr + b0i * ci);
    float s = 1.0f / sqrtf(quad + IP_EPS);
    if (n == 0) { w00r = b0r * s; w00i = -b0i * s; w01r = b1r * s; w01i = -b1i * s; }
    else        { w10r = b0r * s; w10i = -b0i * s; w11r = b1r * s; w11i = -b1i * s; }
  }
  ((float4*)W)[i * 2]     = make_float4(w00r, w00i, w01r, w01i);
  ((float4*)W)[i * 2 + 1] = make_float4(w10r, w10i, w11r, w11i);
}

// ---------------- final: out[n][j][i][2] = Y[i,n,j] ----------------
__global__ __launch_bounds__(256) void k_final(const float2* __restrict__ X,
                                               const float* __restrict__ W,
                                               float2* __restrict__ out) {
  const int i = blockIdx.x * 256 + threadIdx.x;
  if (i >= I_F) return;
  const float4 wa = ((const float4*)W)[i * 2];
  const float4 wb = ((const float4*)W)[i * 2 + 1];
  const int j0 = blockIdx.y * 8;
  const int jend = min(8, J_F - j0);
  for (int jj = 0; jj < jend; ++jj) {
    const int j = j0 + jj;
    float2 x0 = X[(size_t)j * I_F + i];
    float2 x1 = X[(size_t)(J_F + j) * I_F + i];
    float y0r = wa.x * x0.x - wa.y * x0.y + wa.z * x1.x - wa.w * x1.y;
    float y0i = wa.x * x0.y + wa.y * x0.x + wa.z * x1.y + wa.w * x1.x;
    out[(size_t)j * I_F + i] = make_float2(y0r, y0i);
    float y1r = wb.x * x0.x - wb.y * x0.y + wb.z * x1.x - wb.w * x1.y;
    float y1i = wb.x * x0.y + wb.y * x0.x + wb.z * x1.y + wb.w * x1.x;
    out[(size_t)(J_F + j) * I_F + i] = make_float2(y1r, y1i);
  }
}

extern "C" void kernel_launch(void* const* d_in, const int* in_sizes, int n_in,
                              void* d_out, int out_size, void* d_ws, size_t ws_size,
                              hipStream_t stream) {
  const float2* X = (const float2*)d_in[0];
  const float* T0 = (const float*)d_in[1];
  const float* V0 = (const float*)d_in[2];
  char* ws = (char*)d_ws;
  size_t off = 0;
  auto alloc = [&](size_t bytes) -> void* {
    void* p = ws + off;
    off = (off + bytes + 255) & ~(size_t)255;
    return p;
  };
  float* W = (float*)alloc((size_t)I_F * 8 * 4);
  float* T = (float*)alloc((size_t)2 * I_F * K_B * 4);
  float* V = (float*)alloc((size_t)2 * K_B * J_F * 4);
  float* P = (float*)alloc((size_t)2 * I_F * J_F * 4);
  // Tpart (29.5 MB) and Dpart (6.6 MB) have disjoint lifetimes -> share
  float* Scr = (float*)alloc((size_t)2 * PJT * IB * 16 * 4);
  float* Tpart = Scr;
  float* Dpart = Scr;

  k_init<<<128, 256, 0, stream>>>(T0, V0, T, V, W);
  for (int it = 0; it < N_IT; ++it) {
    k_T_partial<<<1800, 256, 0, stream>>>(X, W, T, V, P, Tpart);
    k_t_finish<<<129, 256, 0, stream>>>(Tpart, T);
    k_v_update<<<dim3(1000, 2), 256, 0, stream>>>(P, T, V);
    k_d_partial<<<1800, 256, 0, stream>>>(X, T, V, Dpart);
    k_d_solve<<<9, 256, 0, stream>>>(Dpart, W);
  }
  k_final<<<dim3(9, 250), 256, 0, stream>>>(X, W, (float2*)d_out);
}

// Round 8
// 494.536 us; speedup vs baseline: 1.1227x; 1.1185x over previous
//
#include <hip/hip_runtime.h>
#include <hip/hip_bf16.h>

#define M_CH 2
#define J_F 2000
#define I_F 2049
#define K_B 8
#define N_IT 5
#define NMF_EPS 1e-20f
#define IP_EPS 1e-20f
#define JCH 100     // j-chunks for D partials
#define JCHSZ 20    // 100*20 = 2000 exactly
#define PJT 100     // j-tiles in T-partial kernel
#define PJSZ 20     // 100*20 = 2000 exactly

// ---------------- init: T[n][i][k], V[n][k][j], W[i] = eye ----------------
__global__ void k_init(const float* __restrict__ T0, const float* __restrict__ V0,
                       float* __restrict__ T, float* __restrict__ V, float* __restrict__ W) {
  int t = blockIdx.x * blockDim.x + threadIdx.x;
  int stride = gridDim.x * blockDim.x;
  for (int idx = t; idx < 2 * I_F * K_B; idx += stride) {
    int n = idx / (I_F * K_B);
    int r = idx % (I_F * K_B);
    int i = r / K_B, k = r % K_B;
    T[idx] = T0[(i * K_B + k) * M_CH + n];
  }
  for (int idx = t; idx < 2 * K_B * J_F; idx += stride) {
    int n = idx / (K_B * J_F);
    int r = idx % (K_B * J_F);
    int k = r / J_F, j = r % J_F;
    V[idx] = V0[(k * J_F + j) * M_CH + n];
  }
  for (int i = t; i < I_F; i += stride) {
    W[i * 8 + 0] = 1.f; W[i * 8 + 1] = 0.f; W[i * 8 + 2] = 0.f; W[i * 8 + 3] = 0.f;
    W[i * 8 + 4] = 0.f; W[i * 8 + 5] = 0.f; W[i * 8 + 6] = 1.f; W[i * 8 + 7] = 0.f;
  }
}

// ---------------- pack X into float4 stream: Xp[j][i] = (x0r,x0i,x1r,x1i) ----------------
__global__ __launch_bounds__(256) void k_pack(const float2* __restrict__ X,
                                              float4* __restrict__ Xp) {
  const int i = blockIdx.x * 256 + threadIdx.x;
  if (i >= I_F) return;
  const int j0 = blockIdx.y * 8;
  const int jend = min(8, J_F - j0);
  for (int jj = 0; jj < jend; ++jj) {
    const int j = j0 + jj;
    float2 a = X[(size_t)j * I_F + i];
    float2 b = X[(size_t)(J_F + j) * I_F + i];
    Xp[(size_t)j * I_F + i] = make_float4(a.x, a.y, b.x, b.y);
  }
}

__device__ __forceinline__ float4 load_x(const float4* Xp, const float2* X,
                                         int pk, size_t j, int i) {
  if (pk) return Xp[j * I_F + i];
  float2 a = X[j * I_F + i];
  float2 b = X[(size_t)J_F * I_F + j * I_F + i];
  return make_float4(a.x, a.y, b.x, b.y);
}

// ---- T-update partials; P recomputed inline; flat grid w/ XCD pair-swizzle ----
template<int PK>
__global__ __launch_bounds__(256) void k_T_partial(const float4* __restrict__ Xp,
                                                   const float2* __restrict__ X,
                                                   const float* __restrict__ W,
                                                   const float* __restrict__ T,
                                                   const float* __restrict__ V,
                                                   float* __restrict__ Tpart) {
  // flat 1800 blocks -> (xb 0..8, yb 0..99, n 0..1); (n=0,n=1) pairs same XCD
  const int wid = blockIdx.x;
  const int w = (wid % 8) * 225 + wid / 8;
  const int n = w & 1;
  const int rest = w >> 1;
  const int xb = rest % 9, yb = rest / 9;
  __shared__ float Vl[K_B][PJSZ];
  const int tid = threadIdx.x;
  const int j0 = yb * PJSZ;
  for (int idx = tid; idx < K_B * PJSZ; idx += 256) {
    int k = idx / PJSZ, jj = idx % PJSZ;
    Vl[k][jj] = V[((size_t)n * K_B + k) * J_F + j0 + jj];
  }
  __syncthreads();
  const int i = xb * 256 + tid;
  if (i >= I_F) return;
  float tr[K_B];
#pragma unroll
  for (int k = 0; k < K_B; ++k) tr[k] = T[((size_t)n * I_F + i) * 8 + k];
  const float4 wv4 = ((const float4*)W)[i * 2 + n];
  float num[K_B] = {}, den[K_B] = {};
#pragma unroll 4
  for (int jj = 0; jj < PJSZ; ++jj) {
    float4 x = load_x(Xp, X, PK, (size_t)(j0 + jj), i);
    float yr = wv4.x * x.x - wv4.y * x.y + wv4.z * x.z - wv4.w * x.w;
    float yi = wv4.x * x.y + wv4.y * x.x + wv4.z * x.w + wv4.w * x.z;
    float p = yr * yr + yi * yi;
    float R = 0.f;
#pragma unroll
    for (int k = 0; k < K_B; ++k) R += tr[k] * Vl[k][jj];
    float a = p / (R * R);
    float b = 1.0f / R;
#pragma unroll
    for (int k = 0; k < K_B; ++k) { num[k] += a * Vl[k][jj]; den[k] += b * Vl[k][jj]; }
  }
  float* base_ = Tpart + (((size_t)n * PJT + yb) * I_F + i) * 16;
  *(float4*)(base_ + 0)  = make_float4(num[0], num[1], num[2], num[3]);
  *(float4*)(base_ + 4)  = make_float4(num[4], num[5], num[6], num[7]);
  *(float4*)(base_ + 8)  = make_float4(den[0], den[1], den[2], den[3]);
  *(float4*)(base_ + 12) = make_float4(den[4], den[5], den[6], den[7]);
}

// ---------------- finish T update from partials (ILP-4) ----------------
__global__ __launch_bounds__(256) void k_t_finish(const float* __restrict__ Tpart,
                                                  float* __restrict__ T) {
  int t = blockIdx.x * 256 + threadIdx.x;
  if (t >= 2 * I_F * K_B) return;
  int n = t / (I_F * K_B);
  int r = t % (I_F * K_B);
  int i = r >> 3, k = r & 7;
  const float* p = Tpart + (((size_t)n * PJT) * I_F + i) * 16;
  const size_t S = (size_t)I_F * 16;
  float n0 = 0.f, n1 = 0.f, n2 = 0.f, n3 = 0.f;
  float d0 = 0.f, d1 = 0.f, d2 = 0.f, d3 = 0.f;
  for (int jt = 0; jt < PJT; jt += 4) {
    n0 += p[jt * S + k];       d0 += p[jt * S + 8 + k];
    n1 += p[(jt + 1) * S + k]; d1 += p[(jt + 1) * S + 8 + k];
    n2 += p[(jt + 2) * S + k]; d2 += p[(jt + 2) * S + 8 + k];
    n3 += p[(jt + 3) * S + k]; d3 += p[(jt + 3) * S + 8 + k];
  }
  float num = (n0 + n1) + (n2 + n3);
  float den = (d0 + d1) + (d2 + d3);
  float told = T[t];
  T[t] = fmaxf(told * sqrtf(num / den), NMF_EPS);
}

// -- V update: block per j, both n, recompute P from Xp, full i-reduce, in place --
template<int PK>
__global__ __launch_bounds__(256) void k_v_update(const float4* __restrict__ Xp,
                                                  const float2* __restrict__ X,
                                                  const float* __restrict__ W,
                                                  const float* __restrict__ T,
                                                  float* __restrict__ V) {
  const int j = blockIdx.x;
  const int tid = threadIdx.x;
  float vold0[K_B], vold1[K_B];
#pragma unroll
  for (int k = 0; k < K_B; ++k) {
    vold0[k] = V[(size_t)k * J_F + j];
    vold1[k] = V[(size_t)(K_B + k) * J_F + j];
  }
  float num0[K_B] = {}, den0[K_B] = {}, num1[K_B] = {}, den1[K_B] = {};
  const float* T1 = T + (size_t)I_F * K_B;
  for (int i = tid; i < I_F; i += 256) {
    float4 x = load_x(Xp, X, PK, (size_t)j, i);
    const float4 wa = ((const float4*)W)[i * 2];
    const float4 wb = ((const float4*)W)[i * 2 + 1];
    float yr = wa.x * x.x - wa.y * x.y + wa.z * x.z - wa.w * x.w;
    float yi = wa.x * x.y + wa.y * x.x + wa.z * x.w + wa.w * x.z;
    float p0 = yr * yr + yi * yi;
    float zr = wb.x * x.x - wb.y * x.y + wb.z * x.z - wb.w * x.w;
    float zi = wb.x * x.y + wb.y * x.x + wb.z * x.w + wb.w * x.z;
    float p1 = zr * zr + zi * zi;
    const float4 ta = *(const float4*)&T[i * 8];
    const float4 tb = *(const float4*)&T[i * 8 + 4];
    const float4 tc = *(const float4*)&T1[i * 8];
    const float4 td = *(const float4*)&T1[i * 8 + 4];
    float t0[K_B] = {ta.x, ta.y, ta.z, ta.w, tb.x, tb.y, tb.z, tb.w};
    float t1[K_B] = {tc.x, tc.y, tc.z, tc.w, td.x, td.y, td.z, td.w};
    float R0 = 0.f, R1 = 0.f;
#pragma unroll
    for (int k = 0; k < K_B; ++k) { R0 += t0[k] * vold0[k]; R1 += t1[k] * vold1[k]; }
    float a0 = p0 / (R0 * R0), b0 = 1.0f / R0;
    float a1 = p1 / (R1 * R1), b1 = 1.0f / R1;
#pragma unroll
    for (int k = 0; k < K_B; ++k) {
      num0[k] += a0 * t0[k]; den0[k] += b0 * t0[k];
      num1[k] += a1 * t1[k]; den1[k] += b1 * t1[k];
    }
  }
  __shared__ float red[4][32];
  const int lane = tid & 63, wid = tid >> 6;
#pragma unroll
  for (int k = 0; k < K_B; ++k) {
    float a0 = num0[k], b0 = den0[k], a1 = num1[k], b1 = den1[k];
#pragma unroll
    for (int off = 32; off > 0; off >>= 1) {
      a0 += __shfl_xor(a0, off, 64);
      b0 += __shfl_xor(b0, off, 64);
      a1 += __shfl_xor(a1, off, 64);
      b1 += __shfl_xor(b1, off, 64);
    }
    if (lane == 0) {
      red[wid][k] = a0; red[wid][8 + k] = b0;
      red[wid][16 + k] = a1; red[wid][24 + k] = b1;
    }
  }
  __syncthreads();
  if (tid < 32) red[0][tid] = red[0][tid] + red[1][tid] + red[2][tid] + red[3][tid];
  __syncthreads();
  if (tid < 16) {
    int n = tid >> 3, k = tid & 7;
    float nu = red[0][n * 16 + k];
    float de = red[0][n * 16 + 8 + k];
    size_t idx = ((size_t)n * K_B + k) * J_F + j;
    float vo = V[idx];
    V[idx] = fmaxf(vo * sqrtf(nu / de), NMF_EPS);
  }
}

// -------- weighted covariance partials; flat grid w/ XCD pair-swizzle --------
template<int PK>
__global__ __launch_bounds__(256) void k_d_partial(const float4* __restrict__ Xp,
                                                   const float2* __restrict__ X,
                                                   const float* __restrict__ T,
                                                   const float* __restrict__ V,
                                                   float* __restrict__ Dpart) {
  const int wid = blockIdx.x;
  const int w = (wid % 8) * 225 + wid / 8;
  const int n = w & 1;
  const int rest = w >> 1;
  const int xb = rest % 9, yb = rest / 9;
  __shared__ float Vl[K_B][JCHSZ];
  const int tid = threadIdx.x;
  const int j0 = yb * JCHSZ;
  for (int idx = tid; idx < K_B * JCHSZ; idx += 256) {
    int k = idx / JCHSZ, jj = idx % JCHSZ;
    Vl[k][jj] = V[((size_t)n * K_B + k) * J_F + j0 + jj];
  }
  __syncthreads();
  const int i = xb * 256 + tid;
  if (i >= I_F) return;
  float tr[K_B];
#pragma unroll
  for (int k = 0; k < K_B; ++k) tr[k] = T[((size_t)n * I_F + i) * K_B + k];
  float a00 = 0.f, a11 = 0.f, a01r = 0.f, a01i = 0.f;
#pragma unroll 4
  for (int jj = 0; jj < JCHSZ; ++jj) {
    float4 x = load_x(Xp, X, PK, (size_t)(j0 + jj), i);
    float R = 0.f;
#pragma unroll
    for (int k = 0; k < K_B; ++k) R += tr[k] * Vl[k][jj];
    float wv = 1.0f / (R + IP_EPS);
    a00 += wv * (x.x * x.x + x.y * x.y);
    a11 += wv * (x.z * x.z + x.w * x.w);
    a01r += wv * (x.x * x.z + x.y * x.w);
    a01i += wv * (x.y * x.z - x.x * x.w);
  }
  ((float4*)Dpart)[((size_t)n * JCH + yb) * I_F + i] =
      make_float4(a00, a11, a01r, a01i);
}

// -------- D combine (4 lanes per i) + sequential 2x2 complex solves --------
__global__ __launch_bounds__(256) void k_d_solve(const float* __restrict__ Dpart,
                                                 float* __restrict__ W) {
  const int g = blockIdx.x * 256 + threadIdx.x;
  const int i = g >> 2;
  const int part = g & 3;
  if (i >= I_F) return;
  float4 wa = ((const float4*)W)[i * 2];
  float4 wb = ((const float4*)W)[i * 2 + 1];
  float w00r = wa.x, w00i = wa.y, w01r = wa.z, w01i = wa.w;
  float w10r = wb.x, w10i = wb.y, w11r = wb.z, w11i = wb.w;
  const float invJ = 1.0f / (float)J_F;
#pragma unroll
  for (int n = 0; n < 2; ++n) {
    const float4* dp = (const float4*)Dpart + (size_t)n * JCH * I_F + i;
    float d00 = 0.f, d11 = 0.f, d01r = 0.f, d01i = 0.f;
    for (int c = part * 25; c < part * 25 + 25; ++c) {
      float4 e = dp[(size_t)c * I_F];
      d00 += e.x; d11 += e.y; d01r += e.z; d01i += e.w;
    }
#pragma unroll
    for (int off = 1; off < 4; off <<= 1) {
      d00 += __shfl_xor(d00, off, 64);
      d11 += __shfl_xor(d11, off, 64);
      d01r += __shfl_xor(d01r, off, 64);
      d01i += __shfl_xor(d01i, off, 64);
    }
    d00 = d00 * invJ + IP_EPS;
    d11 = d11 * invJ + IP_EPS;
    d01r *= invJ; d01i *= invJ;
    float A00r = w00r * d00 + (w01r * d01r + w01i * d01i);
    float A00i = w00i * d00 + (w01i * d01r - w01r * d01i);
    float A01r = (w00r * d01r - w00i * d01i) + w01r * d11;
    float A01i = (w00r * d01i + w00i * d01r) + w01i * d11;
    float A10r = w10r * d00 + (w11r * d01r + w11i * d01i);
    float A10i = w10i * d00 + (w11i * d01r - w11r * d01i);
    float A11r = (w10r * d01r - w10i * d01i) + w11r * d11;
    float A11i = (w10r * d01i + w10i * d01r) + w11i * d11;
    float detr = (A00r * A11r - A00i * A11i) - (A01r * A10r - A01i * A10i);
    float deti = (A00r * A11i + A00i * A11r) - (A01r * A10i + A01i * A10r);
    float idet = 1.0f / (detr * detr + deti * deti);
    float n0r, n0i, n1r, n1i;
    if (n == 0) { n0r = A11r; n0i = A11i; n1r = -A10r; n1i = -A10i; }
    else        { n0r = -A01r; n0i = -A01i; n1r = A00r; n1i = A00i; }
    float b0r = (n0r * detr + n0i * deti) * idet;
    float b0i = (n0i * detr - n0r * deti) * idet;
    float b1r = (n1r * detr + n1i * deti) * idet;
    float b1i = (n1i * detr - n1r * deti) * idet;
    float cr = d01r * b1r - d01i * b1i;
    float ci = d01r * b1i + d01i * b1r;
    float quad = d00 * (b0r * b0r + b0i * b0i) + d11 * (b1r * b1r + b1i * b1i)
               + 2.0f * (b0r * cr + b0i * ci);
    float s = 1.0f / sqrtf(quad + IP_EPS);
    if (n == 0) { w00r = b0r * s; w00i = -b0i * s; w01r = b1r * s; w01i = -b1i * s; }
    else        { w10r = b0r * s; w10i = -b0i * s; w11r = b1r * s; w11i = -b1i * s; }
  }
  if (part == 0) {
    ((float4*)W)[i * 2]     = make_float4(w00r, w00i, w01r, w01i);
    ((float4*)W)[i * 2 + 1] = make_float4(w10r, w10i, w11r, w11i);
  }
}

// ---------------- final: out[n][j][i][2] = Y[i,n,j] ----------------
template<int PK>
__global__ __launch_bounds__(256) void k_final(const float4* __restrict__ Xp,
                                               const float2* __restrict__ X,
                                               const float* __restrict__ W,
                                               float2* __restrict__ out) {
  const int i = blockIdx.x * 256 + threadIdx.x;
  if (i >= I_F) return;
  const float4 wa = ((const float4*)W)[i * 2];
  const float4 wb = ((const float4*)W)[i * 2 + 1];
  const int j0 = blockIdx.y * 8;
  const int jend = min(8, J_F - j0);
  for (int jj = 0; jj < jend; ++jj) {
    const int j = j0 + jj;
    float4 x = load_x(Xp, X, PK, (size_t)j, i);
    float y0r = wa.x * x.x - wa.y * x.y + wa.z * x.z - wa.w * x.w;
    float y0i = wa.x * x.y + wa.y * x.x + wa.z * x.w + wa.w * x.z;
    out[(size_t)j * I_F + i] = make_float2(y0r, y0i);
    float y1r = wb.x * x.x - wb.y * x.y + wb.z * x.z - wb.w * x.w;
    float y1i = wb.x * x.y + wb.y * x.x + wb.z * x.w + wb.w * x.z;
    out[(size_t)(J_F + j) * I_F + i] = make_float2(y1r, y1i);
  }
}

extern "C" void kernel_launch(void* const* d_in, const int* in_sizes, int n_in,
                              void* d_out, int out_size, void* d_ws, size_t ws_size,
                              hipStream_t stream) {
  const float2* X = (const float2*)d_in[0];
  const float* T0 = (const float*)d_in[1];
  const float* V0 = (const float*)d_in[2];
  char* ws = (char*)d_ws;
  size_t off = 0;
  auto alloc = [&](size_t bytes) -> void* {
    void* p = ws + off;
    off = (off + bytes + 255) & ~(size_t)255;
    return p;
  };
  float* W = (float*)alloc((size_t)I_F * 8 * 4);
  float* T = (float*)alloc((size_t)2 * I_F * K_B * 4);
  float* V = (float*)alloc((size_t)2 * K_B * J_F * 4);
  // Tpart (26.2 MB) and Dpart (13.1 MB) have disjoint lifetimes -> share
  float* Scr = (float*)alloc((size_t)2 * PJT * I_F * 16 * 4);
  float* Tpart = Scr;
  float* Dpart = Scr;
  size_t off_no_pack = off;
  float4* Xp = (float4*)alloc((size_t)J_F * I_F * 16);
  const bool packed = (off <= ws_size);
  if (!packed) off = off_no_pack;

  k_init<<<128, 256, 0, stream>>>(T0, V0, T, V, W);
  if (packed) {
    k_pack<<<dim3(9, 250), 256, 0, stream>>>(X, Xp);
    for (int it = 0; it < N_IT; ++it) {
      k_T_partial<1><<<1800, 256, 0, stream>>>(Xp, X, W, T, V, Tpart);
      k_t_finish<<<129, 256, 0, stream>>>(Tpart, T);
      k_v_update<1><<<J_F, 256, 0, stream>>>(Xp, X, W, T, V);
      k_d_partial<1><<<1800, 256, 0, stream>>>(Xp, X, T, V, Dpart);
      k_d_solve<<<33, 256, 0, stream>>>(Dpart, W);
    }
    k_final<1><<<dim3(9, 250), 256, 0, stream>>>(Xp, X, W, (float2*)d_out);
  } else {
    for (int it = 0; it < N_IT; ++it) {
      k_T_partial<0><<<1800, 256, 0, stream>>>(nullptr, X, W, T, V, Tpart);
      k_t_finish<<<129, 256, 0, stream>>>(Tpart, T);
      k_v_update<0><<<J_F, 256, 0, stream>>>(nullptr, X, W, T, V);
      k_d_partial<0><<<1800, 256, 0, stream>>>(nullptr, X, T, V, Dpart);
      k_d_solve<<<33, 256, 0, stream>>>(Dpart, W);
    }
    k_final<0><<<dim3(9, 250), 256, 0, stream>>>(nullptr, X, W, (float2*)d_out);
  }
}

// Round 9
// 493.276 us; speedup vs baseline: 1.1255x; 1.0026x over previous
//
#include <hip/hip_runtime.h>
#include <hip/hip_bf16.h>

#define M_CH 2
#define J_F 2000
#define I_F 2049
#define K_B 8
#define N_IT 5
#define NMF_EPS 1e-20f
#define IP_EPS 1e-20f
#define JCH 100     // j-chunks for D partials
#define JCHSZ 20    // 100*20 = 2000 exactly
#define PJT 100     // j-tiles in T-partial kernel
#define PJSZ 20     // 100*20 = 2000 exactly

// bijective XCD swizzle for 900 blocks over 8 XCDs (m204 formula: q=112, r=4)
__device__ __forceinline__ int swz900(int orig) {
  int xcd = orig & 7, rest = orig >> 3;
  return (xcd < 4 ? xcd * 113 : 452 + (xcd - 4) * 112) + rest;
}

// ---------------- init: T[n][i][k], V[n][k][j], W[i] = eye ----------------
__global__ void k_init(const float* __restrict__ T0, const float* __restrict__ V0,
                       float* __restrict__ T, float* __restrict__ V, float* __restrict__ W) {
  int t = blockIdx.x * blockDim.x + threadIdx.x;
  int stride = gridDim.x * blockDim.x;
  for (int idx = t; idx < 2 * I_F * K_B; idx += stride) {
    int n = idx / (I_F * K_B);
    int r = idx % (I_F * K_B);
    int i = r / K_B, k = r % K_B;
    T[idx] = T0[(i * K_B + k) * M_CH + n];
  }
  for (int idx = t; idx < 2 * K_B * J_F; idx += stride) {
    int n = idx / (K_B * J_F);
    int r = idx % (K_B * J_F);
    int k = r / J_F, j = r % J_F;
    V[idx] = V0[(k * J_F + j) * M_CH + n];
  }
  for (int i = t; i < I_F; i += stride) {
    W[i * 8 + 0] = 1.f; W[i * 8 + 1] = 0.f; W[i * 8 + 2] = 0.f; W[i * 8 + 3] = 0.f;
    W[i * 8 + 4] = 0.f; W[i * 8 + 5] = 0.f; W[i * 8 + 6] = 1.f; W[i * 8 + 7] = 0.f;
  }
}

// ------------- pack X: Xp[j][i] = (x0r,x0i,x1r,x1i) -------------
__global__ __launch_bounds__(256) void k_pack(const float2* __restrict__ X,
                                              float4* __restrict__ Xp) {
  const int i = blockIdx.x * 256 + threadIdx.x;
  if (i >= I_F) return;
  const int j0 = blockIdx.y * 8;
  const int jend = min(8, J_F - j0);
  for (int jj = 0; jj < jend; ++jj) {
    const int j = j0 + jj;
    float2 a = X[(size_t)j * I_F + i];
    float2 b = X[(size_t)(J_F + j) * I_F + i];
    Xp[(size_t)j * I_F + i] = make_float4(a.x, a.y, b.x, b.y);
  }
}

__device__ __forceinline__ float4 load_x(const float4* Xp, const float2* X,
                                         int pk, size_t j, int i) {
  if (pk) return Xp[j * I_F + i];
  float2 a = X[j * I_F + i];
  float2 b = X[(size_t)J_F * I_F + j * I_F + i];
  return make_float4(a.x, a.y, b.x, b.y);
}

// ---- T-update partials, BOTH n per thread (1 packed load / ~90 VALU) ----
template<int PK>
__global__ __launch_bounds__(256) void k_T_partial(const float4* __restrict__ Xp,
                                                   const float2* __restrict__ X,
                                                   const float* __restrict__ W,
                                                   const float* __restrict__ T,
                                                   const float* __restrict__ V,
                                                   float* __restrict__ Tpart) {
  const int w = swz900(blockIdx.x);
  const int yb = w / 9, xb = w % 9;
  __shared__ float Vl[2][K_B][PJSZ];
  const int tid = threadIdx.x;
  const int j0 = yb * PJSZ;
  for (int idx = tid; idx < 2 * K_B * PJSZ; idx += 256) {
    int n = idx / (K_B * PJSZ);
    int rr = idx % (K_B * PJSZ);
    int k = rr / PJSZ, jj = rr % PJSZ;
    Vl[n][k][jj] = V[((size_t)n * K_B + k) * J_F + j0 + jj];
  }
  __syncthreads();
  const int i = xb * 256 + tid;
  if (i >= I_F) return;
  float tr0[K_B], tr1[K_B];
#pragma unroll
  for (int k = 0; k < K_B; ++k) {
    tr0[k] = T[(size_t)i * 8 + k];
    tr1[k] = T[((size_t)I_F + i) * 8 + k];
  }
  const float4 w0 = ((const float4*)W)[i * 2];
  const float4 w1 = ((const float4*)W)[i * 2 + 1];
  float num0[K_B] = {}, den0[K_B] = {}, num1[K_B] = {}, den1[K_B] = {};
#pragma unroll 2
  for (int jj = 0; jj < PJSZ; ++jj) {
    float4 x = load_x(Xp, X, PK, (size_t)(j0 + jj), i);
    float yr = w0.x * x.x - w0.y * x.y + w0.z * x.z - w0.w * x.w;
    float yi = w0.x * x.y + w0.y * x.x + w0.z * x.w + w0.w * x.z;
    float p0 = yr * yr + yi * yi;
    float zr = w1.x * x.x - w1.y * x.y + w1.z * x.z - w1.w * x.w;
    float zi = w1.x * x.y + w1.y * x.x + w1.z * x.w + w1.w * x.z;
    float p1 = zr * zr + zi * zi;
    float R0 = 0.f, R1 = 0.f;
#pragma unroll
    for (int k = 0; k < K_B; ++k) {
      R0 += tr0[k] * Vl[0][k][jj];
      R1 += tr1[k] * Vl[1][k][jj];
    }
    float a0 = p0 / (R0 * R0), b0 = 1.0f / R0;
    float a1 = p1 / (R1 * R1), b1 = 1.0f / R1;
#pragma unroll
    for (int k = 0; k < K_B; ++k) {
      num0[k] += a0 * Vl[0][k][jj]; den0[k] += b0 * Vl[0][k][jj];
      num1[k] += a1 * Vl[1][k][jj]; den1[k] += b1 * Vl[1][k][jj];
    }
  }
  float* b0_ = Tpart + (((size_t)0 * PJT + yb) * I_F + i) * 16;
  float* b1_ = Tpart + (((size_t)1 * PJT + yb) * I_F + i) * 16;
  *(float4*)(b0_ + 0)  = make_float4(num0[0], num0[1], num0[2], num0[3]);
  *(float4*)(b0_ + 4)  = make_float4(num0[4], num0[5], num0[6], num0[7]);
  *(float4*)(b0_ + 8)  = make_float4(den0[0], den0[1], den0[2], den0[3]);
  *(float4*)(b0_ + 12) = make_float4(den0[4], den0[5], den0[6], den0[7]);
  *(float4*)(b1_ + 0)  = make_float4(num1[0], num1[1], num1[2], num1[3]);
  *(float4*)(b1_ + 4)  = make_float4(num1[4], num1[5], num1[6], num1[7]);
  *(float4*)(b1_ + 8)  = make_float4(den1[0], den1[1], den1[2], den1[3]);
  *(float4*)(b1_ + 12) = make_float4(den1[4], den1[5], den1[6], den1[7]);
}

// ---------------- finish T update from partials (ILP-4) ----------------
__global__ __launch_bounds__(256) void k_t_finish(const float* __restrict__ Tpart,
                                                  float* __restrict__ T) {
  int t = blockIdx.x * 256 + threadIdx.x;
  if (t >= 2 * I_F * K_B) return;
  int n = t / (I_F * K_B);
  int r = t % (I_F * K_B);
  int i = r >> 3, k = r & 7;
  const float* p = Tpart + (((size_t)n * PJT) * I_F + i) * 16;
  const size_t S = (size_t)I_F * 16;
  float n0 = 0.f, n1 = 0.f, n2 = 0.f, n3 = 0.f;
  float d0 = 0.f, d1 = 0.f, d2 = 0.f, d3 = 0.f;
  for (int jt = 0; jt < PJT; jt += 4) {
    n0 += p[jt * S + k];       d0 += p[jt * S + 8 + k];
    n1 += p[(jt + 1) * S + k]; d1 += p[(jt + 1) * S + 8 + k];
    n2 += p[(jt + 2) * S + k]; d2 += p[(jt + 2) * S + 8 + k];
    n3 += p[(jt + 3) * S + k]; d3 += p[(jt + 3) * S + 8 + k];
  }
  float num = (n0 + n1) + (n2 + n3);
  float den = (d0 + d1) + (d2 + d3);
  float told = T[t];
  T[t] = fmaxf(told * sqrtf(num / den), NMF_EPS);
}

// -- V update: block per j, both n, recompute P from Xp, full i-reduce, in place --
template<int PK>
__global__ __launch_bounds__(256) void k_v_update(const float4* __restrict__ Xp,
                                                  const float2* __restrict__ X,
                                                  const float* __restrict__ W,
                                                  const float* __restrict__ T,
                                                  float* __restrict__ V) {
  const int j = blockIdx.x;
  const int tid = threadIdx.x;
  float vold0[K_B], vold1[K_B];
#pragma unroll
  for (int k = 0; k < K_B; ++k) {
    vold0[k] = V[(size_t)k * J_F + j];
    vold1[k] = V[(size_t)(K_B + k) * J_F + j];
  }
  float num0[K_B] = {}, den0[K_B] = {}, num1[K_B] = {}, den1[K_B] = {};
  const float* T1 = T + (size_t)I_F * K_B;
  for (int i = tid; i < I_F; i += 256) {
    float4 x = load_x(Xp, X, PK, (size_t)j, i);
    const float4 wa = ((const float4*)W)[i * 2];
    const float4 wb = ((const float4*)W)[i * 2 + 1];
    float yr = wa.x * x.x - wa.y * x.y + wa.z * x.z - wa.w * x.w;
    float yi = wa.x * x.y + wa.y * x.x + wa.z * x.w + wa.w * x.z;
    float p0 = yr * yr + yi * yi;
    float zr = wb.x * x.x - wb.y * x.y + wb.z * x.z - wb.w * x.w;
    float zi = wb.x * x.y + wb.y * x.x + wb.z * x.w + wb.w * x.z;
    float p1 = zr * zr + zi * zi;
    const float4 ta = *(const float4*)&T[i * 8];
    const float4 tb = *(const float4*)&T[i * 8 + 4];
    const float4 tc = *(const float4*)&T1[i * 8];
    const float4 td = *(const float4*)&T1[i * 8 + 4];
    float t0[K_B] = {ta.x, ta.y, ta.z, ta.w, tb.x, tb.y, tb.z, tb.w};
    float t1[K_B] = {tc.x, tc.y, tc.z, tc.w, td.x, td.y, td.z, td.w};
    float R0 = 0.f, R1 = 0.f;
#pragma unroll
    for (int k = 0; k < K_B; ++k) { R0 += t0[k] * vold0[k]; R1 += t1[k] * vold1[k]; }
    float a0 = p0 / (R0 * R0), b0 = 1.0f / R0;
    float a1 = p1 / (R1 * R1), b1 = 1.0f / R1;
#pragma unroll
    for (int k = 0; k < K_B; ++k) {
      num0[k] += a0 * t0[k]; den0[k] += b0 * t0[k];
      num1[k] += a1 * t1[k]; den1[k] += b1 * t1[k];
    }
  }
  __shared__ float red[4][32];
  const int lane = tid & 63, wid = tid >> 6;
#pragma unroll
  for (int k = 0; k < K_B; ++k) {
    float a0 = num0[k], b0 = den0[k], a1 = num1[k], b1 = den1[k];
#pragma unroll
    for (int off = 32; off > 0; off >>= 1) {
      a0 += __shfl_xor(a0, off, 64);
      b0 += __shfl_xor(b0, off, 64);
      a1 += __shfl_xor(a1, off, 64);
      b1 += __shfl_xor(b1, off, 64);
    }
    if (lane == 0) {
      red[wid][k] = a0; red[wid][8 + k] = b0;
      red[wid][16 + k] = a1; red[wid][24 + k] = b1;
    }
  }
  __syncthreads();
  if (tid < 32) red[0][tid] = red[0][tid] + red[1][tid] + red[2][tid] + red[3][tid];
  __syncthreads();
  if (tid < 16) {
    int n = tid >> 3, k = tid & 7;
    float nu = red[0][n * 16 + k];
    float de = red[0][n * 16 + 8 + k];
    size_t idx = ((size_t)n * K_B + k) * J_F + j;
    float vo = V[idx];
    V[idx] = fmaxf(vo * sqrtf(nu / de), NMF_EPS);
  }
}

// -------- weighted covariance partials, BOTH n per thread --------
template<int PK>
__global__ __launch_bounds__(256) void k_d_partial(const float4* __restrict__ Xp,
                                                   const float2* __restrict__ X,
                                                   const float* __restrict__ T,
                                                   const float* __restrict__ V,
                                                   float* __restrict__ Dpart) {
  const int w = swz900(blockIdx.x);
  const int yb = w / 9, xb = w % 9;
  __shared__ float Vl[2][K_B][JCHSZ];
  const int tid = threadIdx.x;
  const int j0 = yb * JCHSZ;
  for (int idx = tid; idx < 2 * K_B * JCHSZ; idx += 256) {
    int n = idx / (K_B * JCHSZ);
    int rr = idx % (K_B * JCHSZ);
    int k = rr / JCHSZ, jj = rr % JCHSZ;
    Vl[n][k][jj] = V[((size_t)n * K_B + k) * J_F + j0 + jj];
  }
  __syncthreads();
  const int i = xb * 256 + tid;
  if (i >= I_F) return;
  float tr0[K_B], tr1[K_B];
#pragma unroll
  for (int k = 0; k < K_B; ++k) {
    tr0[k] = T[(size_t)i * K_B + k];
    tr1[k] = T[((size_t)I_F + i) * K_B + k];
  }
  float a00 = 0.f, a11 = 0.f, a01r = 0.f, a01i = 0.f;
  float b00 = 0.f, b11 = 0.f, b01r = 0.f, b01i = 0.f;
#pragma unroll 2
  for (int jj = 0; jj < JCHSZ; ++jj) {
    float4 x = load_x(Xp, X, PK, (size_t)(j0 + jj), i);
    float R0 = 0.f, R1 = 0.f;
#pragma unroll
    for (int k = 0; k < K_B; ++k) {
      R0 += tr0[k] * Vl[0][k][jj];
      R1 += tr1[k] * Vl[1][k][jj];
    }
    float wv0 = 1.0f / (R0 + IP_EPS);
    float wv1 = 1.0f / (R1 + IP_EPS);
    float p00 = x.x * x.x + x.y * x.y;
    float p11 = x.z * x.z + x.w * x.w;
    float pr = x.x * x.z + x.y * x.w;
    float pi = x.y * x.z - x.x * x.w;
    a00 += wv0 * p00; a11 += wv0 * p11; a01r += wv0 * pr; a01i += wv0 * pi;
    b00 += wv1 * p00; b11 += wv1 * p11; b01r += wv1 * pr; b01i += wv1 * pi;
  }
  ((float4*)Dpart)[((size_t)0 * JCH + yb) * I_F + i] = make_float4(a00, a11, a01r, a01i);
  ((float4*)Dpart)[((size_t)1 * JCH + yb) * I_F + i] = make_float4(b00, b11, b01r, b01i);
}

// -------- D combine (4 lanes per i) + sequential 2x2 complex solves --------
__global__ __launch_bounds__(256) void k_d_solve(const float* __restrict__ Dpart,
                                                 float* __restrict__ W) {
  const int g = blockIdx.x * 256 + threadIdx.x;
  const int i = g >> 2;
  const int part = g & 3;
  if (i >= I_F) return;
  float4 wa = ((const float4*)W)[i * 2];
  float4 wb = ((const float4*)W)[i * 2 + 1];
  float w00r = wa.x, w00i = wa.y, w01r = wa.z, w01i = wa.w;
  float w10r = wb.x, w10i = wb.y, w11r = wb.z, w11i = wb.w;
  const float invJ = 1.0f / (float)J_F;
#pragma unroll
  for (int n = 0; n < 2; ++n) {
    const float4* dp = (const float4*)Dpart + (size_t)n * JCH * I_F + i;
    float d00 = 0.f, d11 = 0.f, d01r = 0.f, d01i = 0.f;
    for (int c = part * 25; c < part * 25 + 25; ++c) {
      float4 e = dp[(size_t)c * I_F];
      d00 += e.x; d11 += e.y; d01r += e.z; d01i += e.w;
    }
#pragma unroll
    for (int off = 1; off < 4; off <<= 1) {
      d00 += __shfl_xor(d00, off, 64);
      d11 += __shfl_xor(d11, off, 64);
      d01r += __shfl_xor(d01r, off, 64);
      d01i += __shfl_xor(d01i, off, 64);
    }
    d00 = d00 * invJ + IP_EPS;
    d11 = d11 * invJ + IP_EPS;
    d01r *= invJ; d01i *= invJ;
    float A00r = w00r * d00 + (w01r * d01r + w01i * d01i);
    float A00i = w00i * d00 + (w01i * d01r - w01r * d01i);
    float A01r = (w00r * d01r - w00i * d01i) + w01r * d11;
    float A01i = (w00r * d01i + w00i * d01r) + w01i * d11;
    float A10r = w10r * d00 + (w11r * d01r + w11i * d01i);
    float A10i = w10i * d00 + (w11i * d01r - w11r * d01i);
    float A11r = (w10r * d01r - w10i * d01i) + w11r * d11;
    float A11i = (w10r * d01i + w10i * d01r) + w11i * d11;
    float detr = (A00r * A11r - A00i * A11i) - (A01r * A10r - A01i * A10i);
    float deti = (A00r * A11i + A00i * A11r) - (A01r * A10i + A01i * A10r);
    float idet = 1.0f / (detr * detr + deti * deti);
    float n0r, n0i, n1r, n1i;
    if (n == 0) { n0r = A11r; n0i = A11i; n1r = -A10r; n1i = -A10i; }
    else        { n0r = -A01r; n0i = -A01i; n1r = A00r; n1i = A00i; }
    float b0r = (n0r * detr + n0i * deti) * idet;
    float b0i = (n0i * detr - n0r * deti) * idet;
    float b1r = (n1r * detr + n1i * deti) * idet;
    float b1i = (n1i * detr - n1r * deti) * idet;
    float cr = d01r * b1r - d01i * b1i;
    float ci = d01r * b1i + d01i * b1r;
    float quad = d00 * (b0r * b0r + b0i * b0i) + d11 * (b1r * b1r + b1i * b1i)
               + 2.0f * (b0r * cr + b0i * ci);
    float s = 1.0f / sqrtf(quad + IP_EPS);
    if (n == 0) { w00r = b0r * s; w00i = -b0i * s; w01r = b1r * s; w01i = -b1i * s; }
    else        { w10r = b0r * s; w10i = -b0i * s; w11r = b1r * s; w11i = -b1i * s; }
  }
  if (part == 0) {
    ((float4*)W)[i * 2]     = make_float4(w00r, w00i, w01r, w01i);
    ((float4*)W)[i * 2 + 1] = make_float4(w10r, w10i, w11r, w11i);
  }
}

// ---------------- final: out[n][j][i][2] = Y[i,n,j] ----------------
template<int PK>
__global__ __launch_bounds__(256) void k_final(const float4* __restrict__ Xp,
                                               const float2* __restrict__ X,
                                               const float* __restrict__ W,
                                               float2* __restrict__ out) {
  const int i = blockIdx.x * 256 + threadIdx.x;
  if (i >= I_F) return;
  const float4 wa = ((const float4*)W)[i * 2];
  const float4 wb = ((const float4*)W)[i * 2 + 1];
  const int j0 = blockIdx.y * 8;
  const int jend = min(8, J_F - j0);
  for (int jj = 0; jj < jend; ++jj) {
    const int j = j0 + jj;
    float4 x = load_x(Xp, X, PK, (size_t)j, i);
    float y0r = wa.x * x.x - wa.y * x.y + wa.z * x.z - wa.w * x.w;
    float y0i = wa.x * x.y + wa.y * x.x + wa.z * x.w + wa.w * x.z;
    out[(size_t)j * I_F + i] = make_float2(y0r, y0i);
    float y1r = wb.x * x.x - wb.y * x.y + wb.z * x.z - wb.w * x.w;
    float y1i = wb.x * x.y + wb.y * x.x + wb.z * x.w + wb.w * x.z;
    out[(size_t)(J_F + j) * I_F + i] = make_float2(y1r, y1i);
  }
}

extern "C" void kernel_launch(void* const* d_in, const int* in_sizes, int n_in,
                              void* d_out, int out_size, void* d_ws, size_t ws_size,
                              hipStream_t stream) {
  const float2* X = (const float2*)d_in[0];
  const float* T0 = (const float*)d_in[1];
  const float* V0 = (const float*)d_in[2];
  char* ws = (char*)d_ws;
  size_t off = 0;
  auto alloc = [&](size_t bytes) -> void* {
    void* p = ws + off;
    off = (off + bytes + 255) & ~(size_t)255;
    return p;
  };
  float* W = (float*)alloc((size_t)I_F * 8 * 4);
  float* T = (float*)alloc((size_t)2 * I_F * K_B * 4);
  float* V = (float*)alloc((size_t)2 * K_B * J_F * 4);
  // Tpart (26.2 MB) and Dpart (13.1 MB) have disjoint lifetimes -> share
  float* Scr = (float*)alloc((size_t)2 * PJT * I_F * 16 * 4);
  float* Tpart = Scr;
  float* Dpart = Scr;
  size_t off_no_pack = off;
  float4* Xp = (float4*)alloc((size_t)J_F * I_F * 16);
  const bool packed = (off <= ws_size);
  if (!packed) off = off_no_pack;

  k_init<<<128, 256, 0, stream>>>(T0, V0, T, V, W);
  if (packed) {
    k_pack<<<dim3(9, 250), 256, 0, stream>>>(X, Xp);
    for (int it = 0; it < N_IT; ++it) {
      k_T_partial<1><<<900, 256, 0, stream>>>(Xp, X, W, T, V, Tpart);
      k_t_finish<<<129, 256, 0, stream>>>(Tpart, T);
      k_v_update<1><<<J_F, 256, 0, stream>>>(Xp, X, W, T, V);
      k_d_partial<1><<<900, 256, 0, stream>>>(Xp, X, T, V, Dpart);
      k_d_solve<<<33, 256, 0, stream>>>(Dpart, W);
    }
    k_final<1><<<dim3(9, 250), 256, 0, stream>>>(Xp, X, W, (float2*)d_out);
  } else {
    for (int it = 0; it < N_IT; ++it) {
      k_T_partial<0><<<900, 256, 0, stream>>>(nullptr, X, W, T, V, Tpart);
      k_t_finish<<<129, 256, 0, stream>>>(Tpart, T);
      k_v_update<0><<<J_F, 256, 0, stream>>>(nullptr, X, W, T, V);
      k_d_partial<0><<<900, 256, 0, stream>>>(nullptr, X, T, V, Dpart);
      k_d_solve<<<33, 256, 0, stream>>>(Dpart, W);
    }
    k_final<0><<<dim3(9, 250), 256, 0, stream>>>(nullptr, X, W, (float2*)d_out);
  }
}